// Round 4
// baseline (175.587 us; speedup 1.0000x reference)
//
#include <hip/hip_runtime.h>
#include <math.h>

// FNO 2D spectral conv, MI355X. B=8,H=256,W=256,CIN=COUT=32,M1=M2=16.
// R4: occupancy/latency attack. K1: no LDS x-stage (direct coalesced global
// reads, L2 absorbs the 4-wave intra-block re-read), 4KB self-built twiddle
// LDS, no syncthreads in main path, all-lane stores. K2: direct global T
// reads + self-built U table. k_tw eliminated (tables built in-kernel; E4 for
// K5 generated by 4 extra blocks on K1's grid). K3/K4/K5 as R3 + self-built U.

#define INV_HW (1.0f / 65536.0f)
#define STEP 0.0245436926061702596f  // 2*pi/256

// ------------------------------------------------- K1: w-DFT  x -> T
// blocks 0..2047: bh. blocks 2048..2051: generate E4 table for K5.
// Thread t = kwq*64 + ws*32 + c. T layout [bh][c][kw][2].
__global__ __launch_bounds__(256) void k_wdft(const float* __restrict__ x,
                                              float* __restrict__ T,
                                              float* __restrict__ E4) {
  int bi = blockIdx.x, t = threadIdx.x;
  if (bi >= 2048) {  // E4: [w 128][q 8] float4 (sce*ce, sce*se, sco*co, sco*so)
    int i = (bi - 2048) * 256 + t;  // 0..1023
    int w = i >> 3, q = i & 7;
    int me = (2 * q * w) & 255, mo = ((2 * q + 1) * w) & 255;
    float se, ce, so, co;
    sincosf(STEP * (float)me, &se, &ce);
    sincosf(STEP * (float)mo, &so, &co);
    float sc_e = (q == 0) ? INV_HW : 2.0f * INV_HW;
    float sc_o = 2.0f * INV_HW;
    ((float4*)E4)[i] = make_float4(sc_e * ce, sc_e * se, sc_o * co, sc_o * so);
    return;
  }
  __shared__ __align__(16) float sEo[1024];  // [u 32][kwq 4][8]
  __shared__ __align__(16) float sEi[128];   // [kwq 4][w0 4][8]
  {
    // float4 #t of sEo: t = (u*4+kwq)*2 + half; kw = 4kwq + 2half (+1)
    int half = t & 1, kwq = (t >> 1) & 3, u = t >> 3;
    int kw0 = 4 * kwq + 2 * half, kw1 = kw0 + 1;
    int m0 = (kw0 * 4 * u) & 255, m1 = (kw1 * 4 * u) & 255;
    float s0, c0, s1, c1;
    sincosf(STEP * (float)m0, &s0, &c0);
    sincosf(STEP * (float)m1, &s1, &c1);
    ((float4*)sEo)[t] = make_float4(c0, -s0, c1, -s1);
    if (t < 32) {
      int h2 = t & 1, w0 = (t >> 1) & 3, kq = t >> 3;
      int ka = 4 * kq + 2 * h2, kb = ka + 1;
      int ma = (ka * w0) & 255, mb = (kb * w0) & 255;
      float sa, ca, sb, cb;
      sincosf(STEP * (float)ma, &sa, &ca);
      sincosf(STEP * (float)mb, &sb, &cb);
      ((float4*)sEi)[t] = make_float4(ca, -sa, cb, -sb);
    }
  }
  __syncthreads();
  int kwq = t >> 6, ws = (t >> 5) & 1, c = t & 31;
  float ar[4][4], ai[4][4];
#pragma unroll
  for (int a = 0; a < 4; ++a)
#pragma unroll
    for (int b = 0; b < 4; ++b) { ar[a][b] = 0.f; ai[a][b] = 0.f; }
  const float* xc = x + (size_t)bi * 8192 + c;
#pragma unroll 4
  for (int w1 = 0; w1 < 16; ++w1) {
    int wb = ws * 64 + 4 * w1;
    float xa0 = xc[(wb + 0) * 32], xa1 = xc[(wb + 1) * 32];
    float xa2 = xc[(wb + 2) * 32], xa3 = xc[(wb + 3) * 32];
    float xb0 = xc[(wb + 128) * 32], xb1 = xc[(wb + 129) * 32];
    float xb2 = xc[(wb + 130) * 32], xb3 = xc[(wb + 131) * 32];
    const float4* ep = (const float4*)(sEo + ((ws * 16 + w1) * 4 + kwq) * 8);
    float4 e01 = ep[0], e23 = ep[1];
    float ye, yo;
    ye = xa0 + xb0; yo = xa0 - xb0;
    ar[0][0] += ye * e01.x; ai[0][0] += ye * e01.y;
    ar[0][1] += yo * e01.z; ai[0][1] += yo * e01.w;
    ar[0][2] += ye * e23.x; ai[0][2] += ye * e23.y;
    ar[0][3] += yo * e23.z; ai[0][3] += yo * e23.w;
    ye = xa1 + xb1; yo = xa1 - xb1;
    ar[1][0] += ye * e01.x; ai[1][0] += ye * e01.y;
    ar[1][1] += yo * e01.z; ai[1][1] += yo * e01.w;
    ar[1][2] += ye * e23.x; ai[1][2] += ye * e23.y;
    ar[1][3] += yo * e23.z; ai[1][3] += yo * e23.w;
    ye = xa2 + xb2; yo = xa2 - xb2;
    ar[2][0] += ye * e01.x; ai[2][0] += ye * e01.y;
    ar[2][1] += yo * e01.z; ai[2][1] += yo * e01.w;
    ar[2][2] += ye * e23.x; ai[2][2] += ye * e23.y;
    ar[2][3] += yo * e23.z; ai[2][3] += yo * e23.w;
    ye = xa3 + xb3; yo = xa3 - xb3;
    ar[3][0] += ye * e01.x; ai[3][0] += ye * e01.y;
    ar[3][1] += yo * e01.z; ai[3][1] += yo * e01.w;
    ar[3][2] += ye * e23.x; ai[3][2] += ye * e23.y;
    ar[3][3] += yo * e23.z; ai[3][3] += yo * e23.w;
  }
  const float4* eip = (const float4*)(sEi + kwq * 32);
  float Tr[4] = {0, 0, 0, 0}, Ti[4] = {0, 0, 0, 0};
#pragma unroll
  for (int w0 = 0; w0 < 4; ++w0) {
    float4 g01 = eip[2 * w0], g23 = eip[2 * w0 + 1];
    Tr[0] += ar[w0][0] * g01.x - ai[w0][0] * g01.y;
    Ti[0] += ar[w0][0] * g01.y + ai[w0][0] * g01.x;
    Tr[1] += ar[w0][1] * g01.z - ai[w0][1] * g01.w;
    Ti[1] += ar[w0][1] * g01.w + ai[w0][1] * g01.z;
    Tr[2] += ar[w0][2] * g23.x - ai[w0][2] * g23.y;
    Ti[2] += ar[w0][2] * g23.y + ai[w0][2] * g23.x;
    Tr[3] += ar[w0][3] * g23.z - ai[w0][3] * g23.w;
    Ti[3] += ar[w0][3] * g23.w + ai[w0][3] * g23.z;
  }
#pragma unroll
  for (int j = 0; j < 4; ++j) {
    Tr[j] += __shfl_xor(Tr[j], 32);
    Ti[j] += __shfl_xor(Ti[j], 32);
  }
  // all lanes store one float4: ws picks which half of the kw-quad.
  float4 v = ws ? make_float4(Tr[2], Ti[2], Tr[3], Ti[3])
               : make_float4(Tr[0], Ti[0], Tr[1], Ti[1]);
  *(float4*)(T + (size_t)bi * 1024 + c * 32 + kwq * 8 + ws * 4) = v;
}

// ------------------------------------------------- K2: h-DFT  T -> Xp
// grid (b,c,hq)=1024. Direct global T reads; partial sums over 32 h-pairs.
__global__ __launch_bounds__(256) void k_hdft(const float* __restrict__ T,
                                              float* __restrict__ Xp) {
  __shared__ float2 sU[256];
  int bi = blockIdx.x;
  int b = bi >> 7, c = (bi >> 2) & 31, hq = bi & 3;
  int t = threadIdx.x;
  {
    float s, cc;
    sincosf(STEP * (float)t, &s, &cc);
    sU[t] = make_float2(cc, s);
  }
  __syncthreads();
  int khp = t >> 4, kw = t & 15;
  const float* Tb = T + (size_t)b * 262144 + c * 32 + kw * 2;
  int kha2 = khp + 240;
  float sg = (khp & 1) ? -1.f : 1.f;
  int f0 = hq * 32;
  int ph1 = (khp * f0) & 255, ph2 = (kha2 * f0) & 255;
  float x0r = 0, x0i = 0, x1r = 0, x1i = 0;
#pragma unroll 4
  for (int fl = 0; fl < 32; ++fl) {
    int h = hq * 32 + fl;
    float2 t0 = *(const float2*)(Tb + (size_t)h * 1024);
    float2 t1 = *(const float2*)(Tb + (size_t)(h + 128) * 1024);
    float tpx = fmaf(sg, t1.x, t0.x);
    float tpy = fmaf(sg, t1.y, t0.y);
    float2 e1 = sU[ph1], e2 = sU[ph2];
    x0r += tpx * e1.x + tpy * e1.y;
    x0i += tpy * e1.x - tpx * e1.y;
    x1r += tpx * e2.x + tpy * e2.y;
    x1i += tpy * e2.x - tpx * e2.y;
    ph1 = (ph1 + khp) & 255;
    ph2 = (ph2 + kha2) & 255;
  }
  float2* xb = (float2*)(Xp + (size_t)(hq * 256 + b * 32 + c) * 1024);
  xb[khp * 16 + kw] = make_float2(x0r, x0i);
  xb[(khp + 16) * 16 + kw] = make_float2(x1r, x1i);
}

// ------------------------------------------------- K3: channel mix Xp -> Yp
// grid (b,kh,ih)=512. Sums 4 hq-partials at load; i split over ih + is lanes.
__global__ __launch_bounds__(256) void k_mix(const float* __restrict__ Xp,
                                             const float* __restrict__ wr,
                                             const float* __restrict__ wi_,
                                             float* __restrict__ Yp) {
  __shared__ __align__(16) float sX[1024];  // [i][kw][2]
  int bi = blockIdx.x;
  int b = bi >> 6, kh = (bi >> 1) & 31, ih = bi & 1;
  int blk = kh >> 4, khl = kh & 15;
  int t = threadIdx.x;
  {
    float4 acc = make_float4(0.f, 0.f, 0.f, 0.f);
#pragma unroll
    for (int hq = 0; hq < 4; ++hq) {
      float4 v = *(const float4*)(Xp + (size_t)(hq * 256 + b * 32 + (t >> 3)) * 1024 +
                                  kh * 32 + (t & 7) * 4);
      acc.x += v.x; acc.y += v.y; acc.z += v.z; acc.w += v.w;
    }
    ((float4*)sX)[t] = acc;
  }
  __syncthreads();
  int o = t >> 3, kwq = (t >> 1) & 3, is = t & 1;
  float yr[4] = {0, 0, 0, 0}, yi[4] = {0, 0, 0, 0};
  size_t wbase = (size_t)blk * 262144 + (size_t)o * 256 + khl * 16 + kwq * 4;
#pragma unroll
  for (int ii = 0; ii < 8; ++ii) {
    int i = ih * 16 + is * 8 + ii;
    float4 a = *(const float4*)(wr + wbase + (size_t)i * 8192);
    float4 bb = *(const float4*)(wi_ + wbase + (size_t)i * 8192);
    float4 x01 = *(const float4*)(sX + i * 32 + kwq * 8);
    float4 x23 = *(const float4*)(sX + i * 32 + kwq * 8 + 4);
    yr[0] += x01.x * a.x - x01.y * bb.x; yi[0] += x01.x * bb.x + x01.y * a.x;
    yr[1] += x01.z * a.y - x01.w * bb.y; yi[1] += x01.z * bb.y + x01.w * a.y;
    yr[2] += x23.x * a.z - x23.y * bb.z; yi[2] += x23.x * bb.z + x23.y * a.z;
    yr[3] += x23.z * a.w - x23.w * bb.w; yi[3] += x23.z * bb.w + x23.w * a.w;
  }
#pragma unroll
  for (int j = 0; j < 4; ++j) {
    yr[j] += __shfl_xor(yr[j], 1);
    yi[j] += __shfl_xor(yi[j], 1);
  }
  if (is == 0) {
    float* yp = Yp + (size_t)((ih * 8 + b) * 32 + o) * 1024 + kh * 32 + kwq * 8;
    *(float4*)yp = make_float4(yr[0], yi[0], yr[1], yi[1]);
    *(float4*)(yp + 4) = make_float4(yr[2], yi[2], yr[3], yi[3]);
  }
}

// ------------------------------------------------- K4: h-IDFT  Yp -> G
// grid (b,o,hc)=1024. Sums K3's 2 ih-partials at load. Radix-2: h & h+128.
__global__ __launch_bounds__(256) void k_hidft(const float* __restrict__ Yp,
                                               float* __restrict__ G) {
  __shared__ __align__(16) float4 sY4[256];  // [kh][kwpair]
  __shared__ float2 sU[256];
  int bi = blockIdx.x;
  int b = bi >> 7, o = (bi >> 2) & 31, hc = bi & 3;
  int t = threadIdx.x;
  {
    float4 va = ((const float4*)(Yp + (size_t)(b * 32 + o) * 1024))[t];
    float4 vb = ((const float4*)(Yp + (size_t)(256 + b * 32 + o) * 1024))[t];
    sY4[t] = make_float4(va.x + vb.x, va.y + vb.y, va.z + vb.z, va.w + vb.w);
    float s, cc;
    sincosf(STEP * (float)t, &s, &cc);
    sU[t] = make_float2(cc, s);
  }
  __syncthreads();
  int q = t & 7, hl = t >> 3;
  int h = hc * 32 + hl;
  float se0r = 0, se0i = 0, se1r = 0, se1i = 0;
  float so0r = 0, so0i = 0, so1r = 0, so1i = 0;
#pragma unroll 4
  for (int kh2 = 0; kh2 < 16; ++kh2) {
    int khe = 2 * kh2, kho = khe + 1;
    int khae = khe < 16 ? khe : khe + 224;
    int khao = kho < 16 ? kho : kho + 224;
    float2 ee = sU[(khae * h) & 255];
    float2 eo = sU[(khao * h) & 255];
    float4 yE = sY4[khe * 8 + q];
    float4 yO = sY4[kho * 8 + q];
    se0r += yE.x * ee.x - yE.y * ee.y;
    se0i += yE.x * ee.y + yE.y * ee.x;
    se1r += yE.z * ee.x - yE.w * ee.y;
    se1i += yE.z * ee.y + yE.w * ee.x;
    so0r += yO.x * eo.x - yO.y * eo.y;
    so0i += yO.x * eo.y + yO.y * eo.x;
    so1r += yO.z * eo.x - yO.w * eo.y;
    so1i += yO.z * eo.y + yO.w * eo.x;
  }
  float* g0 = G + (((size_t)b * 256 + h) * 32 + o) * 32 + 4 * q;
  float* g1 = G + (((size_t)b * 256 + h + 128) * 32 + o) * 32 + 4 * q;
  *(float4*)g0 = make_float4(se0r + so0r, se0i + so0i, se1r + so1r, se1i + so1i);
  *(float4*)g1 = make_float4(se0r - so0r, se0i - so0i, se1r - so1r, se1i - so1i);
}

// ------------------------------------------------- K5: w-IDFT (c2r) G -> out
// block=(b,h) 2048. Thread t = og*128 + w: w-major lanes.
__global__ __launch_bounds__(256) void k_widft(const float* __restrict__ G,
                                               const float* __restrict__ E4,
                                               float* __restrict__ out) {
  __shared__ __align__(16) float sG[1024];   // [o][kw][2]
  __shared__ __align__(16) float4 sE4[1024];
  int bh = blockIdx.x, t = threadIdx.x;
  ((float4*)sG)[t] = ((const float4*)(G + (size_t)bh * 1024))[t];
  const float4* e4g = (const float4*)E4;
#pragma unroll
  for (int i = 0; i < 4; ++i) sE4[t + 256 * i] = e4g[t + 256 * i];
  __syncthreads();
  int og = t >> 7, w = t & 127;
  float4 tw[8];
#pragma unroll
  for (int q = 0; q < 8; ++q) tw[q] = sE4[w * 8 + q];
  float* ob = out + (size_t)bh * 8192 + w * 32 + og * 16;
  float* ob2 = ob + 128 * 32;
#pragma unroll
  for (int g4 = 0; g4 < 4; ++g4) {
    float s0[4], s1[4];
#pragma unroll
    for (int k = 0; k < 4; ++k) {
      int o = og * 16 + g4 * 4 + k;
      const float4* gp = (const float4*)(sG + o * 32);
      float se = 0.f, so = 0.f;
#pragma unroll
      for (int q = 0; q < 8; ++q) {
        float4 g = gp[q];
        se += g.x * tw[q].x - g.y * tw[q].y;
        so += g.z * tw[q].z - g.w * tw[q].w;
      }
      s0[k] = se + so;
      s1[k] = se - so;
    }
    *(float4*)(ob + g4 * 4) = make_float4(s0[0], s0[1], s0[2], s0[3]);
    *(float4*)(ob2 + g4 * 4) = make_float4(s1[0], s1[1], s1[2], s1[3]);
  }
}

extern "C" void kernel_launch(void* const* d_in, const int* in_sizes, int n_in,
                              void* d_out, int out_size, void* d_ws, size_t ws_size,
                              hipStream_t stream) {
  const float* x = (const float*)d_in[0];   // [8,256,256,32]
  const float* wr = (const float*)d_in[1];  // [2,32,32,16,16]
  const float* wi = (const float*)d_in[2];
  float* out = (float*)d_out;               // [8,256,256,32]
  float* ws = (float*)d_ws;

  float* E4 = ws;            // 4096 f
  float* T  = ws + 4096;     // 2097152 f  [bh][c][kw][2]
  float* Xp = ws + 2101248;  // 1048576 f  [hq4][b*32+c][kh][kw][2]
  float* Yp = ws + 3149824;  // 524288 f   [ih2][b][o][kh][kw][2]
  float* G  = T;             // reuse (T dead after K2)

  k_wdft<<<2052, 256, 0, stream>>>(x, T, E4);
  k_hdft<<<1024, 256, 0, stream>>>(T, Xp);
  k_mix<<<512, 256, 0, stream>>>(Xp, wr, wi, Yp);
  k_hidft<<<1024, 256, 0, stream>>>(Yp, G);
  k_widft<<<2048, 256, 0, stream>>>(G, E4, out);
}